// Round 5
// baseline (247.894 us; speedup 1.0000x reference)
//
#include <hip/hip_runtime.h>
#include <hip/hip_bf16.h>
#include <cstdint>
#include <cstddef>

// Problem constants (DeepseekV3Experts: T=1024 H=1024 I=1408 E=8 K=4)
#define NE 8
#define NT 1024
#define NK 4
#define NH 1024
#define NI 1408
#define NA (NT * NK)      // 4096 assignments
#define BM 128            // row tile
#define MAXTILES 40
#define PADSLOTS 5120

typedef short short8 __attribute__((ext_vector_type(8)));
typedef float f32x4 __attribute__((ext_vector_type(4)));
typedef float f4v __attribute__((ext_vector_type(4)));
typedef unsigned short u16;

// Workspace layout (bytes).
#define WS_HDR   0
#define WS_SORT  1024
#define WS_XBF   21504      // u16[NT*NH]
#define WS_GT    2118656    // u16[NE*NI*NH]  gate^T [E][I][H]
#define WS_UT    25187328   // u16[NE*NI*NH]  up^T
#define WS_DT    48256000   // u16[NE*NH*NI]  down^T [E][H][I]
#define WS_HB    71324672   // u16[PADSLOTS*NI]

__device__ __forceinline__ u16 f2b(float f) {
  union { float f; uint32_t u; } c; c.f = f;
  uint32_t u = c.u;
  return (u16)((u + 0x7FFFu + ((u >> 16) & 1u)) >> 16);  // RNE
}

__device__ __forceinline__ void llds16(const void* g, void* l) {
  __builtin_amdgcn_global_load_lds(
      (const __attribute__((address_space(1))) void*)g,
      (__attribute__((address_space(3))) void*)l, 16, 0, 0);
}

// Shared transpose-convert stripe: [K][N] fp32 -> [N][K] bf16, 64k x 128n per block.
// LDS tile: stride 64 u16 (128 B) with XOR swizzle col' = col ^ (row & 56).
// (round-4: conflict-free, verified SQ_LDS_BANK_CONFLICT 7.57M -> 1.6K)
__device__ __forceinline__ void transcvt_stripe(const float* __restrict__ src,
                                                u16* __restrict__ dst,
                                                int K, int N, int k0, int n0,
                                                u16* smem, int tid) {
  u16 (*t2)[64][64] = (u16(*)[64][64])smem;
  int r = tid >> 4, c = tid & 15;          // 16 x 16 over (row, col16)
  f4v v[2][4];
#pragma unroll
  for (int t = 0; t < 2; ++t)
#pragma unroll
    for (int i = 0; i < 4; ++i)
      v[t][i] = __builtin_nontemporal_load(
          (const f4v*)&src[(size_t)(k0 + r + 16 * i) * N + n0 + t * 64 + c * 4]);
#pragma unroll
  for (int t = 0; t < 2; ++t)
#pragma unroll
    for (int i = 0; i < 4; ++i) {
      ushort4 o;
      o.x = f2b(v[t][i].x); o.y = f2b(v[t][i].y); o.z = f2b(v[t][i].z); o.w = f2b(v[t][i].w);
      int row = r + 16 * i;
      int sc = (c * 4) ^ (row & 56);
      *(ushort4*)&t2[t][row][sc] = o;
    }
  __syncthreads();
#pragma unroll
  for (int t = 0; t < 2; ++t)
#pragma unroll
    for (int i = 0; i < 2; ++i) {
      int idx = i * 256 + tid;
      int n = idx >> 3, kc = idx & 7;
      int cs = n ^ (kc * 8);
      u16 o[8];
#pragma unroll
      for (int j = 0; j < 8; ++j) o[j] = t2[t][kc * 8 + j][cs];
      *(short8*)&dst[(size_t)(n0 + t * 64 + n) * K + k0 + kc * 8] = *(const short8*)o;
    }
}

// ---------------- K1: all conversions + bucket + out zero (pure HBM-bound work) ----------------
__global__ __launch_bounds__(256) void k1_prep(
    const float* __restrict__ gw, const float* __restrict__ uw, const float* __restrict__ dw,
    const float* __restrict__ hs, const int* __restrict__ sel,
    u16* __restrict__ gT, u16* __restrict__ uT, u16* __restrict__ dT, u16* __restrict__ xbf,
    int* __restrict__ hdr, int* __restrict__ sorted, float* __restrict__ outz) {
  int tid = threadIdx.x;
  int y = blockIdx.y;
  if (y == 24) {  // hidden_states convert (1M elements)
    for (int i = blockIdx.x * 256 + tid; i * 4 < NT * NH; i += 176 * 256) {
      f4v v = __builtin_nontemporal_load((const f4v*)&hs[i * 4]);
      ushort4 o;
      o.x = f2b(v.x); o.y = f2b(v.y); o.z = f2b(v.z); o.w = f2b(v.w);
      *(ushort4*)&xbf[i * 4] = o;
    }
    return;
  }
  if (y == 25) {
    int x = blockIdx.x;
    if (x >= 1 && x <= 64) {  // zero out: 64 blocks x 64 KB
      int base = (x - 1) * 16384;
      f4v z = {0.f, 0.f, 0.f, 0.f};
#pragma unroll
      for (int i = 0; i < 16; ++i)
        *(f4v*)&outz[base + (i * 256 + tid) * 4] = z;
      return;
    }
    if (x != 0) return;
    // bucket (single block)
    __shared__ int cnt[NE], fill[NE], poff_s[NE + 1];
    if (tid < NE) { cnt[tid] = 0; fill[tid] = 0; }
    __syncthreads();
    for (int i = tid; i < NA; i += 256) atomicAdd(&cnt[sel[i]], 1);
    __syncthreads();
    if (tid == 0) {
      int off = 0, nt = 0;
      for (int e = 0; e < NE; ++e) {
        poff_s[e] = off;
        int tiles = (cnt[e] + BM - 1) / BM;
        for (int j = 0; j < tiles; ++j) { hdr[32 + nt] = e; hdr[80 + nt] = off + j * BM; ++nt; }
        off += tiles * BM;
      }
      poff_s[NE] = off;
      hdr[17] = nt;
      for (int e = 0; e < NE; ++e) hdr[e] = cnt[e];
      for (int e = 0; e <= NE; ++e) hdr[8 + e] = poff_s[e];
    }
    __syncthreads();
    for (int i = tid; i < PADSLOTS; i += 256) sorted[i] = -1;
    __syncthreads();
    for (int i = tid; i < NA; i += 256) {
      int e = sel[i];
      int p = atomicAdd(&fill[e], 1);
      sorted[poff_s[e] + p] = i;
    }
    return;
  }
  __shared__ u16 smem[2 * 64 * 64];
  if (y < 16) {   // gate/up: K=NH (16 kb), N=NI (11 nb)
    int tensor = y >> 3, e = y & 7;
    const float* src = ((tensor == 0) ? gw : uw) + (size_t)e * NH * NI;
    u16* dst = ((tensor == 0) ? gT : uT) + (size_t)e * NH * NI;
    int nb = blockIdx.x % 11, kb = blockIdx.x / 11;
    transcvt_stripe(src, dst, NH, NI, kb * 64, nb * 128, smem, tid);
  } else {        // down: K=NI (22 kb), N=NH (8 nb)
    int e = y - 16;
    const float* src = dw + (size_t)e * NI * NH;
    u16* dst = dT + (size_t)e * NI * NH;
    int nb = blockIdx.x % 8, kb = blockIdx.x / 8;
    transcvt_stripe(src, dst, NI, NH, kb * 64, nb * 128, smem, tid);
  }
}

// ---------------- K2: gemm1, 128x128 tile, BK=32, 3-buf depth-2 pipeline ----------------
// T3+T4 (counted vmcnt, never 0 in loop; raw s_barrier, ONE barrier per K-step).
// LDS 72 KB = 3 bufs x (A 8K | Bg 8K | Bu 8K) -> still 2 blocks/CU.
// Per K-step per thread: 6 llds16 (2A+2Bg+2Bu); steady-state vmcnt(6) = next tile in flight.
// Swizzle f(row) = (row&3)^((row>>2)&3) on global source chunk; LDS linear; read un-XORs.
// (2-bit-only swizzle would be 4-way conflict at BK=32; f(row) enumerates to 2-way = free.)
__global__ __launch_bounds__(256, 2) void k2_gemm1(
    const u16* __restrict__ xbf, const u16* __restrict__ gT, const u16* __restrict__ uT,
    u16* __restrict__ hbuf, const int* __restrict__ hdr, const int* __restrict__ sorted) {
  __shared__ u16 smem[36864];   // 72 KB
  int b = blockIdx.x;
  int tid = threadIdx.x;

  int tile = b % 40;
  if (tile >= hdr[17]) return;
  int e = hdr[32 + tile];
  int slot0 = hdr[80 + tile];
  int n0 = (b / 40) * 128;

  // staging sources: chunk idx = s*256+tid; row = idx>>2, c = idx&3 (4 chunks per 32-u16 row)
  const u16* aptr[2];
  const u16 *bgp[2], *bup[2];
#pragma unroll
  for (int s = 0; s < 2; ++s) {
    int idx = s * 256 + tid;
    int row = idx >> 2, c = idx & 3;
    int kc = c ^ (row & 3) ^ ((row >> 2) & 3);
    int as = sorted[slot0 + row];
    int trow = (as >= 0) ? (as >> 2) : 0;
    aptr[s] = xbf + (size_t)trow * NH + kc * 8;
    size_t o = ((size_t)e * NI + n0 + row) * NH + kc * 8;
    bgp[s] = gT + o; bup[s] = uT + o;
  }

  int lane = tid & 63, wave = tid >> 6;
  int wm = wave >> 1, wn = wave & 1;
  int l15 = lane & 15, quad = lane >> 4;
  int pos = ((quad ^ (l15 & 3) ^ ((l15 >> 2) & 3)) & 3) * 8;

  f32x4 accg[4][4] = {}; f32x4 accu[4][4] = {};

  // buf layout (u16): buf*12288 + {A:0, Bg:4096, Bu:8192}
#define K2_STAGE(BUF, KT)                                                \
  {                                                                      \
    int ko_ = (KT) * 32;                                                 \
    u16* p_ = smem + (BUF) * 12288;                                      \
    llds16(aptr[0] + ko_, p_ + tid * 8);                                 \
    llds16(aptr[1] + ko_, p_ + (256 + tid) * 8);                         \
    llds16(bgp[0] + ko_, p_ + 4096 + tid * 8);                           \
    llds16(bgp[1] + ko_, p_ + 4096 + (256 + tid) * 8);                   \
    llds16(bup[0] + ko_, p_ + 8192 + tid * 8);                           \
    llds16(bup[1] + ko_, p_ + 8192 + (256 + tid) * 8);                   \
  }

  K2_STAGE(0, 0);
  K2_STAGE(1, 1);
  for (int kt = 0; kt < 32; ++kt) {
    // wait for tile kt's 6 loads (leave tile kt+1's 6 in flight); 0 only at last step
    if (kt == 31) { asm volatile("s_waitcnt vmcnt(0)" ::: "memory"); }
    else          { asm volatile("s_waitcnt vmcnt(6)" ::: "memory"); }
    __builtin_amdgcn_s_barrier();
    __builtin_amdgcn_sched_barrier(0);
    if (kt < 30) K2_STAGE((kt + 2) % 3, kt + 2);
    const u16* sA  = smem + (kt % 3) * 12288;
    const u16* sBg = sA + 4096;
    const u16* sBu = sA + 8192;
    short8 av[4], bg[4], bu[4];
#pragma unroll
    for (int mf = 0; mf < 4; ++mf)
      av[mf] = *(const short8*)&sA[(wm * 64 + mf * 16 + l15) * 32 + pos];
#pragma unroll
    for (int nf = 0; nf < 4; ++nf) {
      bg[nf] = *(const short8*)&sBg[(wn * 64 + nf * 16 + l15) * 32 + pos];
      bu[nf] = *(const short8*)&sBu[(wn * 64 + nf * 16 + l15) * 32 + pos];
    }
#pragma unroll
    for (int mf = 0; mf < 4; ++mf)
#pragma unroll
      for (int nf = 0; nf < 4; ++nf) {
        accg[mf][nf] = __builtin_amdgcn_mfma_f32_16x16x32_bf16(av[mf], bg[nf], accg[mf][nf], 0, 0, 0);
        accu[mf][nf] = __builtin_amdgcn_mfma_f32_16x16x32_bf16(av[mf], bu[nf], accu[mf][nf], 0, 0, 0);
      }
  }
#undef K2_STAGE

  for (int mf = 0; mf < 4; ++mf)
    for (int nf = 0; nf < 4; ++nf)
      for (int r = 0; r < 4; ++r) {
        int row = wm * 64 + mf * 16 + quad * 4 + r;
        int col = n0 + wn * 64 + nf * 16 + l15;
        float g2 = accg[mf][nf][r], u = accu[mf][nf][r];
        float hv = (g2 / (1.f + __expf(-g2))) * u;
        hbuf[(size_t)(slot0 + row) * NI + col] = f2b(hv);
      }
}

// ---------------- K3: down proj 128x128, BK=32, 3-buf depth-2 pipeline + atomic combine -------
// LDS 48 KB = 3 bufs x (A 8K | B 8K) -> 3 blocks/CU. 4 llds16/thread/tile -> vmcnt(4).
__global__ __launch_bounds__(256, 3) void k3_gemm2(
    const u16* __restrict__ hbuf, const u16* __restrict__ dT,
    const float* __restrict__ rw, float* __restrict__ out,
    const int* __restrict__ hdr, const int* __restrict__ sorted) {
  __shared__ u16 smem[24576];   // 48 KB
  int tile = blockIdx.x;
  if (tile >= hdr[17]) return;
  int e = hdr[32 + tile];
  int slot0 = hdr[80 + tile];
  int n0 = blockIdx.y * 128;
  int tid = threadIdx.x;

  const u16 *ap[2], *bp[2];
#pragma unroll
  for (int s = 0; s < 2; ++s) {
    int idx = s * 256 + tid;
    int row = idx >> 2, c = idx & 3;
    int kc = c ^ (row & 3) ^ ((row >> 2) & 3);
    ap[s] = hbuf + (size_t)(slot0 + row) * NI + kc * 8;
    bp[s] = dT + ((size_t)e * NH + n0 + row) * NI + kc * 8;
  }

  int lane = tid & 63, wave = tid >> 6;
  int wm = wave >> 1, wn = wave & 1;
  int l15 = lane & 15, quad = lane >> 4;
  int pos = ((quad ^ (l15 & 3) ^ ((l15 >> 2) & 3)) & 3) * 8;

  f32x4 acc[4][4] = {};

#define K3_STAGE(BUF, KT)                                                \
  {                                                                      \
    int ko_ = (KT) * 32;                                                 \
    u16* p_ = smem + (BUF) * 8192;                                       \
    llds16(ap[0] + ko_, p_ + tid * 8);                                   \
    llds16(ap[1] + ko_, p_ + (256 + tid) * 8);                           \
    llds16(bp[0] + ko_, p_ + 4096 + tid * 8);                            \
    llds16(bp[1] + ko_, p_ + 4096 + (256 + tid) * 8);                    \
  }

  K3_STAGE(0, 0);
  K3_STAGE(1, 1);
  for (int kt = 0; kt < 44; ++kt) {
    if (kt == 43) { asm volatile("s_waitcnt vmcnt(0)" ::: "memory"); }
    else          { asm volatile("s_waitcnt vmcnt(4)" ::: "memory"); }
    __builtin_amdgcn_s_barrier();
    __builtin_amdgcn_sched_barrier(0);
    if (kt < 42) K3_STAGE((kt + 2) % 3, kt + 2);
    const u16* sA = smem + (kt % 3) * 8192;
    const u16* sB = sA + 4096;
    short8 av[4], bv[4];
#pragma unroll
    for (int mf = 0; mf < 4; ++mf)
      av[mf] = *(const short8*)&sA[(wm * 64 + mf * 16 + l15) * 32 + pos];
#pragma unroll
    for (int nf = 0; nf < 4; ++nf)
      bv[nf] = *(const short8*)&sB[(wn * 64 + nf * 16 + l15) * 32 + pos];
#pragma unroll
    for (int mf = 0; mf < 4; ++mf)
#pragma unroll
      for (int nf = 0; nf < 4; ++nf)
        acc[mf][nf] = __builtin_amdgcn_mfma_f32_16x16x32_bf16(av[mf], bv[nf], acc[mf][nf], 0, 0, 0);
  }
#undef K3_STAGE

  // weighted combine: out[token] += rw[assignment] * down_row
  for (int mf = 0; mf < 4; ++mf) {
    int rowb = wm * 64 + mf * 16 + quad * 4;
    for (int r = 0; r < 4; ++r) {
      int as = sorted[slot0 + rowb + r];
      if (as < 0) continue;
      float w = rw[as];
      float* orow = out + (size_t)(as >> 2) * NH + n0 + wn * 64;
      for (int nf = 0; nf < 4; ++nf)
        atomicAdd(&orow[nf * 16 + l15], w * acc[mf][nf][r]);
    }
  }
}

extern "C" void kernel_launch(void* const* d_in, const int* in_sizes, int n_in,
                              void* d_out, int out_size, void* d_ws, size_t ws_size,
                              hipStream_t stream) {
  const float* hs  = (const float*)d_in[0];
  const float* rw  = (const float*)d_in[1];
  const float* gw  = (const float*)d_in[2];
  const float* uw  = (const float*)d_in[3];
  const float* dw  = (const float*)d_in[4];
  const int*   sel = (const int*)d_in[5];
  float* out = (float*)d_out;

  char* ws = (char*)d_ws;
  int*  hdr    = (int*)(ws + WS_HDR);
  int*  sorted = (int*)(ws + WS_SORT);
  u16*  xbf    = (u16*)(ws + WS_XBF);
  u16*  gT     = (u16*)(ws + WS_GT);
  u16*  uT     = (u16*)(ws + WS_UT);
  u16*  dT     = (u16*)(ws + WS_DT);
  u16*  hb     = (u16*)(ws + WS_HB);

  hipLaunchKernelGGL(k1_prep, dim3(176, 26), dim3(256), 0, stream,
                     gw, uw, dw, hs, sel, gT, uT, dT, xbf, hdr, sorted, out);
  hipLaunchKernelGGL(k2_gemm1, dim3(440), dim3(256), 0, stream,
                     xbf, gT, uT, hb, hdr, sorted);
  hipLaunchKernelGGL(k3_gemm2, dim3(MAXTILES, NH / 128), dim3(256), 0, stream,
                     hb, dT, rw, out, hdr, sorted);
}

// Round 6
// 239.418 us; speedup vs baseline: 1.0354x; 1.0354x over previous
//
#include <hip/hip_runtime.h>
#include <hip/hip_bf16.h>
#include <cstdint>
#include <cstddef>

// Problem constants (DeepseekV3Experts: T=1024 H=1024 I=1408 E=8 K=4)
#define NE 8
#define NT 1024
#define NK 4
#define NH 1024
#define NI 1408
#define NA (NT * NK)      // 4096 assignments
#define BM 128            // row tile
#define MAXTILES 40
#define PADSLOTS 5120

typedef short short8 __attribute__((ext_vector_type(8)));
typedef float f32x4 __attribute__((ext_vector_type(4)));
typedef float f4v __attribute__((ext_vector_type(4)));
typedef unsigned short u16;

// Workspace layout (bytes).
#define WS_HDR   0
#define WS_SORT  1024
#define WS_XBF   21504      // u16[NT*NH]
#define WS_GT    2118656    // u16[NE*NI*NH]  gate^T [E][I][H]; dead after k2 -> reused as part[] (fp32)
#define WS_UT    25187328   // u16[NE*NI*NH]  up^T
#define WS_DT    48256000   // u16[NE*NH*NI]  down^T [E][H][I]
#define WS_HB    71324672   // u16[PADSLOTS*NI]
// slotOf[NA] lives in hbuf's guaranteed-unused tail: padded slot count =
// sum_e ceil(c_e/128) <= floor(32 + 8*127/128) = 39 tiles -> slots <= 4992,
// so hbuf rows [4992,5120) are never written by k2/read by k3.
#define WS_SLOT  (WS_HB + 4992 * NI * 2)   // int[NA] (16 KB), ends < old footprint

__device__ __forceinline__ u16 f2b(float f) {
  union { float f; uint32_t u; } c; c.f = f;
  uint32_t u = c.u;
  return (u16)((u + 0x7FFFu + ((u >> 16) & 1u)) >> 16);  // RNE
}

__device__ __forceinline__ void llds16(const void* g, void* l) {
  __builtin_amdgcn_global_load_lds(
      (const __attribute__((address_space(1))) void*)g,
      (__attribute__((address_space(3))) void*)l, 16, 0, 0);
}

// Shared transpose-convert stripe: [K][N] fp32 -> [N][K] bf16, 64k x 128n per block.
// LDS tile: stride 64 u16 (128 B) with XOR swizzle col' = col ^ (row & 56).
// (round-4: conflict-free, verified SQ_LDS_BANK_CONFLICT 7.57M -> 1.6K)
__device__ __forceinline__ void transcvt_stripe(const float* __restrict__ src,
                                                u16* __restrict__ dst,
                                                int K, int N, int k0, int n0,
                                                u16* smem, int tid) {
  u16 (*t2)[64][64] = (u16(*)[64][64])smem;
  int r = tid >> 4, c = tid & 15;          // 16 x 16 over (row, col16)
  f4v v[2][4];
#pragma unroll
  for (int t = 0; t < 2; ++t)
#pragma unroll
    for (int i = 0; i < 4; ++i)
      v[t][i] = __builtin_nontemporal_load(
          (const f4v*)&src[(size_t)(k0 + r + 16 * i) * N + n0 + t * 64 + c * 4]);
#pragma unroll
  for (int t = 0; t < 2; ++t)
#pragma unroll
    for (int i = 0; i < 4; ++i) {
      ushort4 o;
      o.x = f2b(v[t][i].x); o.y = f2b(v[t][i].y); o.z = f2b(v[t][i].z); o.w = f2b(v[t][i].w);
      int row = r + 16 * i;
      int sc = (c * 4) ^ (row & 56);
      *(ushort4*)&t2[t][row][sc] = o;
    }
  __syncthreads();
#pragma unroll
  for (int t = 0; t < 2; ++t)
#pragma unroll
    for (int i = 0; i < 2; ++i) {
      int idx = i * 256 + tid;
      int n = idx >> 3, kc = idx & 7;
      int cs = n ^ (kc * 8);
      u16 o[8];
#pragma unroll
      for (int j = 0; j < 8; ++j) o[j] = t2[t][kc * 8 + j][cs];
      *(short8*)&dst[(size_t)(n0 + t * 64 + n) * K + k0 + kc * 8] = *(const short8*)o;
    }
}

// ---------------- K1: all conversions + bucket (out-zero removed; k4 overwrites out) -------
__global__ __launch_bounds__(256) void k1_prep(
    const float* __restrict__ gw, const float* __restrict__ uw, const float* __restrict__ dw,
    const float* __restrict__ hs, const int* __restrict__ sel,
    u16* __restrict__ gT, u16* __restrict__ uT, u16* __restrict__ dT, u16* __restrict__ xbf,
    int* __restrict__ hdr, int* __restrict__ sorted, int* __restrict__ slotOf) {
  int tid = threadIdx.x;
  int y = blockIdx.y;
  if (y == 24) {  // hidden_states convert (1M elements)
    for (int i = blockIdx.x * 256 + tid; i * 4 < NT * NH; i += 176 * 256) {
      f4v v = __builtin_nontemporal_load((const f4v*)&hs[i * 4]);
      ushort4 o;
      o.x = f2b(v.x); o.y = f2b(v.y); o.z = f2b(v.z); o.w = f2b(v.w);
      *(ushort4*)&xbf[i * 4] = o;
    }
    return;
  }
  if (y == 25) {
    if (blockIdx.x != 0) return;
    // bucket (single block)
    __shared__ int cnt[NE], fill[NE], poff_s[NE + 1];
    if (tid < NE) { cnt[tid] = 0; fill[tid] = 0; }
    __syncthreads();
    for (int i = tid; i < NA; i += 256) atomicAdd(&cnt[sel[i]], 1);
    __syncthreads();
    if (tid == 0) {
      int off = 0, nt = 0;
      for (int e = 0; e < NE; ++e) {
        poff_s[e] = off;
        int tiles = (cnt[e] + BM - 1) / BM;
        for (int j = 0; j < tiles; ++j) { hdr[32 + nt] = e; hdr[80 + nt] = off + j * BM; ++nt; }
        off += tiles * BM;
      }
      poff_s[NE] = off;
      hdr[17] = nt;
      for (int e = 0; e < NE; ++e) hdr[e] = cnt[e];
      for (int e = 0; e <= NE; ++e) hdr[8 + e] = poff_s[e];
    }
    __syncthreads();
    for (int i = tid; i < PADSLOTS; i += 256) sorted[i] = -1;
    __syncthreads();
    for (int i = tid; i < NA; i += 256) {
      int e = sel[i];
      int p = atomicAdd(&fill[e], 1);
      int s = poff_s[e] + p;
      sorted[s] = i;
      slotOf[i] = s;
    }
    return;
  }
  __shared__ u16 smem[2 * 64 * 64];
  if (y < 16) {   // gate/up: K=NH (16 kb), N=NI (11 nb)
    int tensor = y >> 3, e = y & 7;
    const float* src = ((tensor == 0) ? gw : uw) + (size_t)e * NH * NI;
    u16* dst = ((tensor == 0) ? gT : uT) + (size_t)e * NH * NI;
    int nb = blockIdx.x % 11, kb = blockIdx.x / 11;
    transcvt_stripe(src, dst, NH, NI, kb * 64, nb * 128, smem, tid);
  } else {        // down: K=NI (22 kb), N=NH (8 nb)
    int e = y - 16;
    const float* src = dw + (size_t)e * NI * NH;
    u16* dst = dT + (size_t)e * NI * NH;
    int nb = blockIdx.x % 8, kb = blockIdx.x / 8;
    transcvt_stripe(src, dst, NI, NH, kb * 64, nb * 128, smem, tid);
  }
}

// ---------------- K2: gemm1, 128x128 tile, BK=32, 3-buf depth-2 pipeline, XCD swizzle -------
// T1: XCD x (= b%8) gets 55 contiguous jobs (tile-major) -> each XCD covers ~1.4 n-columns
// of all experts' B panels (~5.5 MB, near-L2-resident) instead of round-robin thrash
// (r1 measured FETCH 124 MB vs ~54 ideal).
__global__ __launch_bounds__(256, 2) void k2_gemm1(
    const u16* __restrict__ xbf, const u16* __restrict__ gT, const u16* __restrict__ uT,
    u16* __restrict__ hbuf, const int* __restrict__ hdr, const int* __restrict__ sorted) {
  __shared__ u16 smem[36864];   // 72 KB
  int b = blockIdx.x;
  int tid = threadIdx.x;

  int job = (b & 7) * 55 + (b >> 3);   // bijective for 440 = 8*55
  int tile = job % 40;
  if (tile >= hdr[17]) return;
  int e = hdr[32 + tile];
  int slot0 = hdr[80 + tile];
  int n0 = (job / 40) * 128;

  const u16* aptr[2];
  const u16 *bgp[2], *bup[2];
#pragma unroll
  for (int s = 0; s < 2; ++s) {
    int idx = s * 256 + tid;
    int row = idx >> 2, c = idx & 3;
    int kc = c ^ (row & 3) ^ ((row >> 2) & 3);
    int as = sorted[slot0 + row];
    int trow = (as >= 0) ? (as >> 2) : 0;
    aptr[s] = xbf + (size_t)trow * NH + kc * 8;
    size_t o = ((size_t)e * NI + n0 + row) * NH + kc * 8;
    bgp[s] = gT + o; bup[s] = uT + o;
  }

  int lane = tid & 63, wave = tid >> 6;
  int wm = wave >> 1, wn = wave & 1;
  int l15 = lane & 15, quad = lane >> 4;
  int pos = ((quad ^ (l15 & 3) ^ ((l15 >> 2) & 3)) & 3) * 8;

  f32x4 accg[4][4] = {}; f32x4 accu[4][4] = {};

#define K2_STAGE(BUF, KT)                                                \
  {                                                                      \
    int ko_ = (KT) * 32;                                                 \
    u16* p_ = smem + (BUF) * 12288;                                      \
    llds16(aptr[0] + ko_, p_ + tid * 8);                                 \
    llds16(aptr[1] + ko_, p_ + (256 + tid) * 8);                         \
    llds16(bgp[0] + ko_, p_ + 4096 + tid * 8);                           \
    llds16(bgp[1] + ko_, p_ + 4096 + (256 + tid) * 8);                   \
    llds16(bup[0] + ko_, p_ + 8192 + tid * 8);                           \
    llds16(bup[1] + ko_, p_ + 8192 + (256 + tid) * 8);                   \
  }

  K2_STAGE(0, 0);
  K2_STAGE(1, 1);
  for (int kt = 0; kt < 32; ++kt) {
    if (kt == 31) { asm volatile("s_waitcnt vmcnt(0)" ::: "memory"); }
    else          { asm volatile("s_waitcnt vmcnt(6)" ::: "memory"); }
    __builtin_amdgcn_s_barrier();
    __builtin_amdgcn_sched_barrier(0);
    if (kt < 30) K2_STAGE((kt + 2) % 3, kt + 2);
    const u16* sA  = smem + (kt % 3) * 12288;
    const u16* sBg = sA + 4096;
    const u16* sBu = sA + 8192;
    short8 av[4], bg[4], bu[4];
#pragma unroll
    for (int mf = 0; mf < 4; ++mf)
      av[mf] = *(const short8*)&sA[(wm * 64 + mf * 16 + l15) * 32 + pos];
#pragma unroll
    for (int nf = 0; nf < 4; ++nf) {
      bg[nf] = *(const short8*)&sBg[(wn * 64 + nf * 16 + l15) * 32 + pos];
      bu[nf] = *(const short8*)&sBu[(wn * 64 + nf * 16 + l15) * 32 + pos];
    }
#pragma unroll
    for (int mf = 0; mf < 4; ++mf)
#pragma unroll
      for (int nf = 0; nf < 4; ++nf) {
        accg[mf][nf] = __builtin_amdgcn_mfma_f32_16x16x32_bf16(av[mf], bg[nf], accg[mf][nf], 0, 0, 0);
        accu[mf][nf] = __builtin_amdgcn_mfma_f32_16x16x32_bf16(av[mf], bu[nf], accu[mf][nf], 0, 0, 0);
      }
  }
#undef K2_STAGE

  for (int mf = 0; mf < 4; ++mf)
    for (int nf = 0; nf < 4; ++nf)
      for (int r = 0; r < 4; ++r) {
        int row = wm * 64 + mf * 16 + quad * 4 + r;
        int col = n0 + wn * 64 + nf * 16 + l15;
        float g2 = accg[mf][nf][r], u = accu[mf][nf][r];
        float hv = (g2 / (1.f + __expf(-g2))) * u;
        hbuf[(size_t)(slot0 + row) * NI + col] = f2b(hv);
      }
}

// ---------------- K3: down proj 128x128, BK=32, 3-buf pipeline, XCD-sliced, NO atomics -----
// T1: b%8 = n-slice index -> XCD x reads only dT[:, x*128:(x+1)*128] (2.9 MB, L2-resident).
// Atomic combine replaced by conflict-free fp32 partial stores: part[slot][col] = w*acc
// (slots unique per (tile, n0) -> no collisions). k4 sums each token's 4 slots.
__global__ __launch_bounds__(256, 3) void k3_gemm2(
    const u16* __restrict__ hbuf, const u16* __restrict__ dT,
    const float* __restrict__ rw, float* __restrict__ part,
    const int* __restrict__ hdr, const int* __restrict__ sorted) {
  __shared__ u16 smem[24576];   // 48 KB
  int b = blockIdx.x;           // 320 = 8 n-slices * 40 tiles
  int tile = b >> 3;
  if (tile >= hdr[17]) return;
  int e = hdr[32 + tile];
  int slot0 = hdr[80 + tile];
  int n0 = (b & 7) * 128;
  int tid = threadIdx.x;

  const u16 *ap[2], *bp[2];
#pragma unroll
  for (int s = 0; s < 2; ++s) {
    int idx = s * 256 + tid;
    int row = idx >> 2, c = idx & 3;
    int kc = c ^ (row & 3) ^ ((row >> 2) & 3);
    ap[s] = hbuf + (size_t)(slot0 + row) * NI + kc * 8;
    bp[s] = dT + ((size_t)e * NH + n0 + row) * NI + kc * 8;
  }

  int lane = tid & 63, wave = tid >> 6;
  int wm = wave >> 1, wn = wave & 1;
  int l15 = lane & 15, quad = lane >> 4;
  int pos = ((quad ^ (l15 & 3) ^ ((l15 >> 2) & 3)) & 3) * 8;

  f32x4 acc[4][4] = {};

#define K3_STAGE(BUF, KT)                                                \
  {                                                                      \
    int ko_ = (KT) * 32;                                                 \
    u16* p_ = smem + (BUF) * 8192;                                       \
    llds16(ap[0] + ko_, p_ + tid * 8);                                   \
    llds16(ap[1] + ko_, p_ + (256 + tid) * 8);                           \
    llds16(bp[0] + ko_, p_ + 4096 + tid * 8);                            \
    llds16(bp[1] + ko_, p_ + 4096 + (256 + tid) * 8);                    \
  }

  K3_STAGE(0, 0);
  K3_STAGE(1, 1);
  for (int kt = 0; kt < 44; ++kt) {
    if (kt == 43) { asm volatile("s_waitcnt vmcnt(0)" ::: "memory"); }
    else          { asm volatile("s_waitcnt vmcnt(4)" ::: "memory"); }
    __builtin_amdgcn_s_barrier();
    __builtin_amdgcn_sched_barrier(0);
    if (kt < 42) K3_STAGE((kt + 2) % 3, kt + 2);
    const u16* sA = smem + (kt % 3) * 8192;
    const u16* sB = sA + 4096;
    short8 av[4], bv[4];
#pragma unroll
    for (int mf = 0; mf < 4; ++mf)
      av[mf] = *(const short8*)&sA[(wm * 64 + mf * 16 + l15) * 32 + pos];
#pragma unroll
    for (int nf = 0; nf < 4; ++nf)
      bv[nf] = *(const short8*)&sB[(wn * 64 + nf * 16 + l15) * 32 + pos];
#pragma unroll
    for (int mf = 0; mf < 4; ++mf)
#pragma unroll
      for (int nf = 0; nf < 4; ++nf)
        acc[mf][nf] = __builtin_amdgcn_mfma_f32_16x16x32_bf16(av[mf], bv[nf], acc[mf][nf], 0, 0, 0);
  }
#undef K3_STAGE

  // weighted partial store: part[slot][col] = rw[assignment] * down_row (no collisions)
  for (int mf = 0; mf < 4; ++mf) {
    int rowb = wm * 64 + mf * 16 + quad * 4;
    for (int r = 0; r < 4; ++r) {
      int slot = slot0 + rowb + r;
      int as = sorted[slot];
      if (as < 0) continue;
      float w = rw[as];
      float* prow = part + (size_t)slot * NH + n0 + wn * 64;
      for (int nf = 0; nf < 4; ++nf)
        prow[nf * 16 + l15] = w * acc[mf][nf][r];
    }
  }
}

// ---------------- K4: per-token combine: out[t] = sum_k part[slotOf[4t+k]] ----------------
// Grid 512 x 256: block = 2 tokens, thread = 8 cols. ~25 MB traffic, ~4-5 us.
__global__ __launch_bounds__(256) void k4_combine(
    const float* __restrict__ part, const int* __restrict__ slotOf,
    float* __restrict__ out) {
  int tid = threadIdx.x;
  int token = blockIdx.x * 2 + (tid >> 7);
  int col0 = (tid & 127) * 8;
  const int* sl = slotOf + token * 4;
  f4v a0 = {0.f, 0.f, 0.f, 0.f}, a1 = {0.f, 0.f, 0.f, 0.f};
#pragma unroll
  for (int k = 0; k < 4; ++k) {
    const float* pr = part + (size_t)sl[k] * NH + col0;
    a0 += *(const f4v*)pr;
    a1 += *(const f4v*)(pr + 4);
  }
  float* o = out + (size_t)token * NH + col0;
  *(f4v*)o = a0;
  *(f4v*)(o + 4) = a1;
}

extern "C" void kernel_launch(void* const* d_in, const int* in_sizes, int n_in,
                              void* d_out, int out_size, void* d_ws, size_t ws_size,
                              hipStream_t stream) {
  const float* hs  = (const float*)d_in[0];
  const float* rw  = (const float*)d_in[1];
  const float* gw  = (const float*)d_in[2];
  const float* uw  = (const float*)d_in[3];
  const float* dw  = (const float*)d_in[4];
  const int*   sel = (const int*)d_in[5];
  float* out = (float*)d_out;

  char* ws = (char*)d_ws;
  int*  hdr    = (int*)(ws + WS_HDR);
  int*  sorted = (int*)(ws + WS_SORT);
  u16*  xbf    = (u16*)(ws + WS_XBF);
  u16*  gT     = (u16*)(ws + WS_GT);
  u16*  uT     = (u16*)(ws + WS_UT);
  u16*  dT     = (u16*)(ws + WS_DT);
  u16*  hb     = (u16*)(ws + WS_HB);
  float* part  = (float*)(ws + WS_GT);    // reuse gT region (dead after k2); 21 MB <= 23 MB
  int*  slotOf = (int*)(ws + WS_SLOT);    // hbuf tail rows [4992,5120) (never staged)

  hipLaunchKernelGGL(k1_prep, dim3(176, 26), dim3(256), 0, stream,
                     gw, uw, dw, hs, sel, gT, uT, dT, xbf, hdr, sorted, slotOf);
  hipLaunchKernelGGL(k2_gemm1, dim3(440), dim3(256), 0, stream,
                     xbf, gT, uT, hb, hdr, sorted);
  hipLaunchKernelGGL(k3_gemm2, dim3(320), dim3(256), 0, stream,
                     hb, dT, rw, part, hdr, sorted);
  hipLaunchKernelGGL(k4_combine, dim3(512), dim3(256), 0, stream,
                     part, slotOf, out);
}

// Round 7
// 237.108 us; speedup vs baseline: 1.0455x; 1.0097x over previous
//
#include <hip/hip_runtime.h>
#include <hip/hip_bf16.h>
#include <cstdint>
#include <cstddef>

// Problem constants (DeepseekV3Experts: T=1024 H=1024 I=1408 E=8 K=4)
#define NE 8
#define NT 1024
#define NK 4
#define NH 1024
#define NI 1408
#define NA (NT * NK)      // 4096 assignments
#define BM 128            // row tile
#define MAXTILES 40
#define PADSLOTS 5120

typedef short short8 __attribute__((ext_vector_type(8)));
typedef float f32x4 __attribute__((ext_vector_type(4)));
typedef float f4v __attribute__((ext_vector_type(4)));
typedef unsigned short u16;

// Workspace layout (bytes).
#define WS_HDR   0
#define WS_SORT  1024
#define WS_XBF   21504      // u16[NT*NH]
#define WS_GT    2118656    // u16[NE*NI*NH]  gate^T; dead after k2 -> part[2] planes (2x21 MB <= 44 MB of gT+uT)
#define WS_UT    25187328   // u16[NE*NI*NH]  up^T
#define WS_DT    48256000   // u16[NE*NH*NI]  down^T [E][H][I]
#define WS_HB    71324672   // u16[PADSLOTS*NI]
// slotOf[NA] in hbuf's guaranteed-unused tail (padded slots <= 4992 < 5120).
#define WS_SLOT  (WS_HB + 4992 * NI * 2)   // int[NA]
#define PART_PLANE (PADSLOTS * NH)         // floats per part plane (5120*1024)

__device__ __forceinline__ u16 f2b(float f) {
  union { float f; uint32_t u; } c; c.f = f;
  uint32_t u = c.u;
  return (u16)((u + 0x7FFFu + ((u >> 16) & 1u)) >> 16);  // RNE
}

__device__ __forceinline__ void llds16(const void* g, void* l) {
  __builtin_amdgcn_global_load_lds(
      (const __attribute__((address_space(1))) void*)g,
      (__attribute__((address_space(3))) void*)l, 16, 0, 0);
}

// Shared transpose-convert stripe: [K][N] fp32 -> [N][K] bf16, 64k x 128n per block.
// LDS tile: stride 64 u16 (128 B) with XOR swizzle col' = col ^ (row & 56).
// (round-4: conflict-free, verified SQ_LDS_BANK_CONFLICT 7.57M -> 1.6K)
__device__ __forceinline__ void transcvt_stripe(const float* __restrict__ src,
                                                u16* __restrict__ dst,
                                                int K, int N, int k0, int n0,
                                                u16* smem, int tid) {
  u16 (*t2)[64][64] = (u16(*)[64][64])smem;
  int r = tid >> 4, c = tid & 15;          // 16 x 16 over (row, col16)
  f4v v[2][4];
#pragma unroll
  for (int t = 0; t < 2; ++t)
#pragma unroll
    for (int i = 0; i < 4; ++i)
      v[t][i] = __builtin_nontemporal_load(
          (const f4v*)&src[(size_t)(k0 + r + 16 * i) * N + n0 + t * 64 + c * 4]);
#pragma unroll
  for (int t = 0; t < 2; ++t)
#pragma unroll
    for (int i = 0; i < 4; ++i) {
      ushort4 o;
      o.x = f2b(v[t][i].x); o.y = f2b(v[t][i].y); o.z = f2b(v[t][i].z); o.w = f2b(v[t][i].w);
      int row = r + 16 * i;
      int sc = (c * 4) ^ (row & 56);
      *(ushort4*)&t2[t][row][sc] = o;
    }
  __syncthreads();
#pragma unroll
  for (int t = 0; t < 2; ++t)
#pragma unroll
    for (int i = 0; i < 2; ++i) {
      int idx = i * 256 + tid;
      int n = idx >> 3, kc = idx & 7;
      int cs = n ^ (kc * 8);
      u16 o[8];
#pragma unroll
      for (int j = 0; j < 8; ++j) o[j] = t2[t][kc * 8 + j][cs];
      *(short8*)&dst[(size_t)(n0 + t * 64 + n) * K + k0 + kc * 8] = *(const short8*)o;
    }
}

// ---------------- K1: all conversions + bucket ----------------
__global__ __launch_bounds__(256) void k1_prep(
    const float* __restrict__ gw, const float* __restrict__ uw, const float* __restrict__ dw,
    const float* __restrict__ hs, const int* __restrict__ sel,
    u16* __restrict__ gT, u16* __restrict__ uT, u16* __restrict__ dT, u16* __restrict__ xbf,
    int* __restrict__ hdr, int* __restrict__ sorted, int* __restrict__ slotOf) {
  int tid = threadIdx.x;
  int y = blockIdx.y;
  if (y == 24) {  // hidden_states convert (1M elements)
    for (int i = blockIdx.x * 256 + tid; i * 4 < NT * NH; i += 176 * 256) {
      f4v v = __builtin_nontemporal_load((const f4v*)&hs[i * 4]);
      ushort4 o;
      o.x = f2b(v.x); o.y = f2b(v.y); o.z = f2b(v.z); o.w = f2b(v.w);
      *(ushort4*)&xbf[i * 4] = o;
    }
    return;
  }
  if (y == 25) {
    if (blockIdx.x != 0) return;
    // bucket (single block)
    __shared__ int cnt[NE], fill[NE], poff_s[NE + 1];
    if (tid < NE) { cnt[tid] = 0; fill[tid] = 0; }
    __syncthreads();
    for (int i = tid; i < NA; i += 256) atomicAdd(&cnt[sel[i]], 1);
    __syncthreads();
    if (tid == 0) {
      int off = 0, nt = 0;
      for (int e = 0; e < NE; ++e) {
        poff_s[e] = off;
        int tiles = (cnt[e] + BM - 1) / BM;
        for (int j = 0; j < tiles; ++j) { hdr[32 + nt] = e; hdr[80 + nt] = off + j * BM; ++nt; }
        off += tiles * BM;
      }
      poff_s[NE] = off;
      hdr[17] = nt;
      for (int e = 0; e < NE; ++e) hdr[e] = cnt[e];
      for (int e = 0; e <= NE; ++e) hdr[8 + e] = poff_s[e];
    }
    __syncthreads();
    for (int i = tid; i < PADSLOTS; i += 256) sorted[i] = -1;
    __syncthreads();
    for (int i = tid; i < NA; i += 256) {
      int e = sel[i];
      int p = atomicAdd(&fill[e], 1);
      int s = poff_s[e] + p;
      sorted[s] = i;
      slotOf[i] = s;
    }
    return;
  }
  __shared__ u16 smem[2 * 64 * 64];
  if (y < 16) {   // gate/up: K=NH (16 kb), N=NI (11 nb)
    int tensor = y >> 3, e = y & 7;
    const float* src = ((tensor == 0) ? gw : uw) + (size_t)e * NH * NI;
    u16* dst = ((tensor == 0) ? gT : uT) + (size_t)e * NH * NI;
    int nb = blockIdx.x % 11, kb = blockIdx.x / 11;
    transcvt_stripe(src, dst, NH, NI, kb * 64, nb * 128, smem, tid);
  } else {        // down: K=NI (22 kb), N=NH (8 nb)
    int e = y - 16;
    const float* src = dw + (size_t)e * NI * NH;
    u16* dst = dT + (size_t)e * NI * NH;
    int nb = blockIdx.x % 8, kb = blockIdx.x / 8;
    transcvt_stripe(src, dst, NI, NH, kb * 64, nb * 128, smem, tid);
  }
}

// ---------------- K2: gemm1, 128x128 tile, BK=32, 3-buf depth-2 pipeline, XCD swizzle -------
// (unchanged from round 6)
__global__ __launch_bounds__(256, 2) void k2_gemm1(
    const u16* __restrict__ xbf, const u16* __restrict__ gT, const u16* __restrict__ uT,
    u16* __restrict__ hbuf, const int* __restrict__ hdr, const int* __restrict__ sorted) {
  __shared__ u16 smem[36864];   // 72 KB
  int b = blockIdx.x;
  int tid = threadIdx.x;

  int job = (b & 7) * 55 + (b >> 3);   // bijective for 440 = 8*55
  int tile = job % 40;
  if (tile >= hdr[17]) return;
  int e = hdr[32 + tile];
  int slot0 = hdr[80 + tile];
  int n0 = (job / 40) * 128;

  const u16* aptr[2];
  const u16 *bgp[2], *bup[2];
#pragma unroll
  for (int s = 0; s < 2; ++s) {
    int idx = s * 256 + tid;
    int row = idx >> 2, c = idx & 3;
    int kc = c ^ (row & 3) ^ ((row >> 2) & 3);
    int as = sorted[slot0 + row];
    int trow = (as >= 0) ? (as >> 2) : 0;
    aptr[s] = xbf + (size_t)trow * NH + kc * 8;
    size_t o = ((size_t)e * NI + n0 + row) * NH + kc * 8;
    bgp[s] = gT + o; bup[s] = uT + o;
  }

  int lane = tid & 63, wave = tid >> 6;
  int wm = wave >> 1, wn = wave & 1;
  int l15 = lane & 15, quad = lane >> 4;
  int pos = ((quad ^ (l15 & 3) ^ ((l15 >> 2) & 3)) & 3) * 8;

  f32x4 accg[4][4] = {}; f32x4 accu[4][4] = {};

#define K2_STAGE(BUF, KT)                                                \
  {                                                                      \
    int ko_ = (KT) * 32;                                                 \
    u16* p_ = smem + (BUF) * 12288;                                      \
    llds16(aptr[0] + ko_, p_ + tid * 8);                                 \
    llds16(aptr[1] + ko_, p_ + (256 + tid) * 8);                         \
    llds16(bgp[0] + ko_, p_ + 4096 + tid * 8);                           \
    llds16(bgp[1] + ko_, p_ + 4096 + (256 + tid) * 8);                   \
    llds16(bup[0] + ko_, p_ + 8192 + tid * 8);                           \
    llds16(bup[1] + ko_, p_ + 8192 + (256 + tid) * 8);                   \
  }

  K2_STAGE(0, 0);
  K2_STAGE(1, 1);
  for (int kt = 0; kt < 32; ++kt) {
    if (kt == 31) { asm volatile("s_waitcnt vmcnt(0)" ::: "memory"); }
    else          { asm volatile("s_waitcnt vmcnt(6)" ::: "memory"); }
    __builtin_amdgcn_s_barrier();
    __builtin_amdgcn_sched_barrier(0);
    if (kt < 30) K2_STAGE((kt + 2) % 3, kt + 2);
    const u16* sA  = smem + (kt % 3) * 12288;
    const u16* sBg = sA + 4096;
    const u16* sBu = sA + 8192;
    short8 av[4], bg[4], bu[4];
#pragma unroll
    for (int mf = 0; mf < 4; ++mf)
      av[mf] = *(const short8*)&sA[(wm * 64 + mf * 16 + l15) * 32 + pos];
#pragma unroll
    for (int nf = 0; nf < 4; ++nf) {
      bg[nf] = *(const short8*)&sBg[(wn * 64 + nf * 16 + l15) * 32 + pos];
      bu[nf] = *(const short8*)&sBu[(wn * 64 + nf * 16 + l15) * 32 + pos];
    }
#pragma unroll
    for (int mf = 0; mf < 4; ++mf)
#pragma unroll
      for (int nf = 0; nf < 4; ++nf) {
        accg[mf][nf] = __builtin_amdgcn_mfma_f32_16x16x32_bf16(av[mf], bg[nf], accg[mf][nf], 0, 0, 0);
        accu[mf][nf] = __builtin_amdgcn_mfma_f32_16x16x32_bf16(av[mf], bu[nf], accu[mf][nf], 0, 0, 0);
      }
  }
#undef K2_STAGE

  for (int mf = 0; mf < 4; ++mf)
    for (int nf = 0; nf < 4; ++nf)
      for (int r = 0; r < 4; ++r) {
        int row = wm * 64 + mf * 16 + quad * 4 + r;
        int col = n0 + wn * 64 + nf * 16 + l15;
        float g2 = accg[mf][nf][r], u = accu[mf][nf][r];
        float hv = (g2 / (1.f + __expf(-g2))) * u;
        hbuf[(size_t)(slot0 + row) * NI + col] = f2b(hv);
      }
}

// ---------------- K3: down proj 128x128, BK=32, K-SPLIT-2, XCD-sliced, NO atomics ----------
// Grid 640 = 8 n-slices (b&7, XCD-aligned: each XCD keeps one 128-col dT slice L2-resident)
// x 40 tiles x 2 K-halves. K-split doubles resident blocks/CU (1.25 -> 2.5): cross-block
// overlap hides staging latency (m114) without touching the proven 256-thr 3-buf skeleton.
// Each K-half writes its own part plane (still collision-free, no zero-init needed:
// every real slot is written in BOTH planes). k4 sums 8 partials.
__global__ __launch_bounds__(256, 3) void k3_gemm2(
    const u16* __restrict__ hbuf, const u16* __restrict__ dT,
    const float* __restrict__ rw, float* __restrict__ part,
    const int* __restrict__ hdr, const int* __restrict__ sorted) {
  __shared__ u16 smem[24576];   // 48 KB
  int b = blockIdx.x;
  int nsl = b & 7;
  int r = b >> 3;
  int tile = r % 40;
  int kh = r / 40;              // 0/1: K-steps [0,22) / [22,44)
  if (tile >= hdr[17]) return;
  int e = hdr[32 + tile];
  int slot0 = hdr[80 + tile];
  int n0 = nsl * 128;
  int tid = threadIdx.x;

  const u16 *ap[2], *bp[2];
#pragma unroll
  for (int s = 0; s < 2; ++s) {
    int idx = s * 256 + tid;
    int row = idx >> 2, c = idx & 3;
    int kc = c ^ (row & 3) ^ ((row >> 2) & 3);
    ap[s] = hbuf + (size_t)(slot0 + row) * NI + kc * 8;
    bp[s] = dT + ((size_t)e * NH + n0 + row) * NI + kc * 8;
  }

  int lane = tid & 63, wave = tid >> 6;
  int wm = wave >> 1, wn = wave & 1;
  int l15 = lane & 15, quad = lane >> 4;
  int pos = ((quad ^ (l15 & 3) ^ ((l15 >> 2) & 3)) & 3) * 8;

  f32x4 acc[4][4] = {};

#define K3_STAGE(BUF, KT)                                                \
  {                                                                      \
    int ko_ = (KT) * 32;                                                 \
    u16* p_ = smem + (BUF) * 8192;                                       \
    llds16(ap[0] + ko_, p_ + tid * 8);                                   \
    llds16(ap[1] + ko_, p_ + (256 + tid) * 8);                           \
    llds16(bp[0] + ko_, p_ + 4096 + tid * 8);                            \
    llds16(bp[1] + ko_, p_ + 4096 + (256 + tid) * 8);                    \
  }

  int kt0 = kh * 22;
  K3_STAGE(0, kt0);
  K3_STAGE(1, kt0 + 1);
  for (int kt = 0; kt < 22; ++kt) {
    if (kt == 21) { asm volatile("s_waitcnt vmcnt(0)" ::: "memory"); }
    else          { asm volatile("s_waitcnt vmcnt(4)" ::: "memory"); }
    __builtin_amdgcn_s_barrier();
    __builtin_amdgcn_sched_barrier(0);
    if (kt < 20) K3_STAGE((kt + 2) % 3, kt0 + kt + 2);
    const u16* sA = smem + (kt % 3) * 8192;
    const u16* sB = sA + 4096;
    short8 av[4], bv[4];
#pragma unroll
    for (int mf = 0; mf < 4; ++mf)
      av[mf] = *(const short8*)&sA[(wm * 64 + mf * 16 + l15) * 32 + pos];
#pragma unroll
    for (int nf = 0; nf < 4; ++nf)
      bv[nf] = *(const short8*)&sB[(wn * 64 + nf * 16 + l15) * 32 + pos];
#pragma unroll
    for (int mf = 0; mf < 4; ++mf)
#pragma unroll
      for (int nf = 0; nf < 4; ++nf)
        acc[mf][nf] = __builtin_amdgcn_mfma_f32_16x16x32_bf16(av[mf], bv[nf], acc[mf][nf], 0, 0, 0);
  }
#undef K3_STAGE

  // weighted partial store into this K-half's plane (no collisions)
  float* plane = part + (size_t)kh * PART_PLANE;
  for (int mf = 0; mf < 4; ++mf) {
    int rowb = wm * 64 + mf * 16 + quad * 4;
    for (int rr = 0; rr < 4; ++rr) {
      int slot = slot0 + rowb + rr;
      int as = sorted[slot];
      if (as < 0) continue;
      float w = rw[as];
      float* prow = plane + (size_t)slot * NH + n0 + wn * 64;
      for (int nf = 0; nf < 4; ++nf)
        prow[nf * 16 + l15] = w * acc[mf][nf][rr];
    }
  }
}

// ---------------- K4: per-token combine: out[t] = sum_{k,kh} part[kh][slotOf[4t+k]] --------
__global__ __launch_bounds__(256) void k4_combine(
    const float* __restrict__ part, const int* __restrict__ slotOf,
    float* __restrict__ out) {
  int tid = threadIdx.x;
  int token = blockIdx.x * 2 + (tid >> 7);
  int col0 = (tid & 127) * 8;
  const int* sl = slotOf + token * 4;
  f4v a0 = {0.f, 0.f, 0.f, 0.f}, a1 = {0.f, 0.f, 0.f, 0.f};
#pragma unroll
  for (int k = 0; k < 4; ++k) {
    size_t ro = (size_t)sl[k] * NH + col0;
    const float* p0 = part + ro;
    const float* p1 = part + (size_t)PART_PLANE + ro;
    a0 += *(const f4v*)p0;
    a1 += *(const f4v*)(p0 + 4);
    a0 += *(const f4v*)p1;
    a1 += *(const f4v*)(p1 + 4);
  }
  float* o = out + (size_t)token * NH + col0;
  *(f4v*)o = a0;
  *(f4v*)(o + 4) = a1;
}

extern "C" void kernel_launch(void* const* d_in, const int* in_sizes, int n_in,
                              void* d_out, int out_size, void* d_ws, size_t ws_size,
                              hipStream_t stream) {
  const float* hs  = (const float*)d_in[0];
  const float* rw  = (const float*)d_in[1];
  const float* gw  = (const float*)d_in[2];
  const float* uw  = (const float*)d_in[3];
  const float* dw  = (const float*)d_in[4];
  const int*   sel = (const int*)d_in[5];
  float* out = (float*)d_out;

  char* ws = (char*)d_ws;
  int*  hdr    = (int*)(ws + WS_HDR);
  int*  sorted = (int*)(ws + WS_SORT);
  u16*  xbf    = (u16*)(ws + WS_XBF);
  u16*  gT     = (u16*)(ws + WS_GT);
  u16*  uT     = (u16*)(ws + WS_UT);
  u16*  dT     = (u16*)(ws + WS_DT);
  u16*  hb     = (u16*)(ws + WS_HB);
  float* part  = (float*)(ws + WS_GT);    // 2 planes x 21 MB in gT+uT region (dead after k2)
  int*  slotOf = (int*)(ws + WS_SLOT);    // hbuf tail rows [4992,5120)

  hipLaunchKernelGGL(k1_prep, dim3(176, 26), dim3(256), 0, stream,
                     gw, uw, dw, hs, sel, gT, uT, dT, xbf, hdr, sorted, slotOf);
  hipLaunchKernelGGL(k2_gemm1, dim3(440), dim3(256), 0, stream,
                     xbf, gT, uT, hb, hdr, sorted);
  hipLaunchKernelGGL(k3_gemm2, dim3(640), dim3(256), 0, stream,
                     hb, dT, rw, part, hdr, sorted);
  hipLaunchKernelGGL(k4_combine, dim3(512), dim3(256), 0, stream,
                     part, slotOf, out);
}